// Round 7
// baseline (301.346 us; speedup 1.0000x reference)
//
#include <hip/hip_runtime.h>
#include <hip/hip_bf16.h>

// B=64, C=1, H=W=1024, KS=16, F=128, OUT=10, L=4096, K=256
#define B_    64
#define F_    128
#define L_    4096
#define K_    256
#define OUT_  10
#define HW_   (1024 * 1024)
#define WIMG_ 1024
#define NL    4              // consecutive l's per block
#define NBLK  (L_ / NL)      // 1024 blocks
#define YPAD  136            // ym row stride in u16 (16B-aligned, 8-sweep floor)

typedef __attribute__((ext_vector_type(8))) short bf16x8;   // MFMA A/B frag
typedef __attribute__((ext_vector_type(4))) float f32x4;    // MFMA C/D frag

static __device__ __forceinline__ unsigned short f2bf(float f) {
    return __builtin_bit_cast(unsigned short, __float2bfloat16(f));
}
static __device__ __forceinline__ float bf2f(unsigned short h) {
    unsigned int i = ((unsigned int)h) << 16;
    return __builtin_bit_cast(float, i);
}
static __device__ __forceinline__ bf16x8 cvt8(float4 a, float4 b) {
    bf16x8 r;
    r[0] = (short)f2bf(a.x); r[1] = (short)f2bf(a.y);
    r[2] = (short)f2bf(a.z); r[3] = (short)f2bf(a.w);
    r[4] = (short)f2bf(b.x); r[5] = (short)f2bf(b.y);
    r[6] = (short)f2bf(b.z); r[7] = (short)f2bf(b.w);
    return r;
}

// ---------------------------------------------------------------------------
// l-CHUNKED: one block per 4 consecutive l's (same hb row). 512 thr = 8 waves.
// KEY CHANGE vs R4/R5: each lane's w-stream is now 4KB sequential (w[f][l][k]
// contiguous in l), testing the DRAM row-buffer/stream-locality hypothesis.
// Per l: stage x -> LDS bf16 (swizzled) | b1 | wave wv: f in [wv*16,+16),
// stream w global->reg->B-frag, acc[4] over 64 b | ym (bf16) | b2 | fused
// decoder accumulates part[4b][5o] across l's. End: red + one partial/block.
// LDS 49KB static (< 64KB limit that killed R6).
// ---------------------------------------------------------------------------
__global__ __launch_bounds__(512)
void lcn_main(const float* __restrict__ x, const float* __restrict__ wgt,
              const float* __restrict__ bias, const float* __restrict__ dec_w,
              float* __restrict__ ws) {
    const int blk = blockIdx.x;
    const int hbi = blk >> 4;            // 0..63
    const int wq  = blk & 15;            // chunk within row
    const int l0  = hbi * 64 + wq * NL;
    const int t   = threadIdx.x;
    const int lane = t & 63;
    const int wv   = t >> 6;             // wave 0..7 = f-group
    const int ln15 = lane & 15;
    const int kg   = lane >> 4;
    const int fme  = wv * 16 + ln15;     // this lane's f

    __shared__ union {
        struct {
            unsigned short xs[B_ * K_];      // 32 KB, swizzled k ^= (b&7)<<3
            unsigned short ym[B_ * YPAD];    // 17 KB, y tile bf16
        } s;
        float red[16][B_][OUT_];             // 40 KB (after l-loop)
    } u;

    // staging map: thread (sb, jl)
    const int sb = t >> 3;               // batch 0..63
    const int jl = t & 7;
    const float* xrow = x + (size_t)sb * HW_ + (size_t)(hbi * 16) * WIMG_;
    const int swzs = (sb & 7) << 3;

    // w row pointer for this lane's f, first l of chunk
    const float* wrow = wgt + ((size_t)fme * L_ + l0) * K_;

    // decoder map
    const int tt = t & 255;
    const int oh = t >> 8;               // o-half: 0 -> o0..4, 1 -> o5..9
    const int tx = tt & 15, ty = tt >> 4;
    const int b0 = tx * 4, f0 = ty * 8;

    float part[4][5];
    #pragma unroll
    for (int bi = 0; bi < 4; ++bi)
        #pragma unroll
        for (int oo = 0; oo < 5; ++oo) part[bi][oo] = 0.f;

    for (int il = 0; il < NL; ++il) {
        const int l = l0 + il;

        // ---- stage x(l): 64b x 256k -> bf16 LDS ----
        {
            const float* xp = xrow + (size_t)(wq * NL + il) * 16;
            #pragma unroll
            for (int c = 0; c < 4; ++c) {
                const int k0  = c * 64 + jl * 8;
                const int row = k0 >> 4, col = k0 & 15;
                float4 v0 = *reinterpret_cast<const float4*>(xp + (size_t)row * WIMG_ + col);
                float4 v1 = *reinterpret_cast<const float4*>(xp + (size_t)row * WIMG_ + col + 4);
                *reinterpret_cast<bf16x8*>(&u.s.xs[sb * K_ + (k0 ^ swzs)]) = cvt8(v0, v1);
            }
        }
        __syncthreads();   // b1: xs ready (also: all decoder(l-1) reads done)

        // ---- MFMA: this wave's 16 f's x all 64 b ----
        f32x4 acc[4];
        #pragma unroll
        for (int m = 0; m < 4; ++m) acc[m] = (f32x4){0.f, 0.f, 0.f, 0.f};

        const float* wl = wrow + (size_t)il * K_;
        #pragma unroll
        for (int ks = 0; ks < 8; ++ks) {
            const int kb = ks * 32 + kg * 8;
            float4 w0 = *reinterpret_cast<const float4*>(wl + kb);
            float4 w1 = *reinterpret_cast<const float4*>(wl + kb + 4);
            const bf16x8 bw = cvt8(w0, w1);
            bf16x8 a[4];
            #pragma unroll
            for (int m = 0; m < 4; ++m) {
                const int b = m * 16 + ln15;
                a[m] = *reinterpret_cast<const bf16x8*>(
                    &u.s.xs[b * K_ + (kb ^ ((b & 7) << 3))]);
            }
            #pragma unroll
            for (int m = 0; m < 4; ++m)
                acc[m] = __builtin_amdgcn_mfma_f32_16x16x32_bf16(a[m], bw, acc[m], 0, 0, 0);
        }

        // ---- bias + ReLU -> ym (bf16) ----
        const float bv = bias[(size_t)fme * L_ + l];
        #pragma unroll
        for (int m = 0; m < 4; ++m)
            #pragma unroll
            for (int r = 0; r < 4; ++r) {
                const int b = m * 16 + kg * 4 + r;   // C/D: row=(lane>>4)*4+reg
                u.s.ym[b * YPAD + fme] = f2bf(fmaxf(acc[m][r] + bv, 0.f));
            }
        __syncthreads();   // b2: ym ready for cross-wave decoder

        // ---- fused decoder: accumulate part over this l ----
        float yv[4][8];
        #pragma unroll
        for (int bi = 0; bi < 4; ++bi) {
            bf16x8 yb = *reinterpret_cast<const bf16x8*>(&u.s.ym[(b0 + bi) * YPAD + f0]);
            #pragma unroll
            for (int e = 0; e < 8; ++e)
                yv[bi][e] = bf2f((unsigned short)yb[e]);
        }
        #pragma unroll
        for (int fj = 0; fj < 8; ++fj) {
            #pragma unroll
            for (int oo = 0; oo < 5; ++oo) {
                const int o = oh * 5 + oo;
                const float dw = dec_w[(size_t)o * ((size_t)F_ * L_) + (size_t)(f0 + fj) * L_ + l];
                #pragma unroll
                for (int bi = 0; bi < 4; ++bi)
                    part[bi][oo] = fmaf(yv[bi][fj], dw, part[bi][oo]);
            }
        }
        // next stage(l+1) writes xs only; ym reads above are guarded by b1(l+1)
    }

    __syncthreads();   // l-loop LDS dead; red aliases it
    #pragma unroll
    for (int bi = 0; bi < 4; ++bi)
        #pragma unroll
        for (int oo = 0; oo < 5; ++oo)
            u.red[ty][b0 + bi][oh * 5 + oo] = part[bi][oo];
    __syncthreads();

    for (int idx = t; idx < B_ * OUT_; idx += 512) {
        const int b = idx / OUT_;
        const int o = idx - b * OUT_;
        float s = 0.f;
        #pragma unroll
        for (int g = 0; g < 16; ++g) s += u.red[g][b][o];
        ws[((size_t)b * NBLK + blk) * OUT_ + o] = s;   // ws[b][blk][o]
    }
}

// ---------------------------------------------------------------------------
// Kernel B: reduce ws[b][1024][10] over chunks, add dec_b.
// ---------------------------------------------------------------------------
__global__ __launch_bounds__(640)
void lcn_reduce(const float* __restrict__ ws, const float* __restrict__ dec_b,
                float* __restrict__ out) {
    const int b = blockIdx.x;
    const int j = threadIdx.x;            // 0..639
    const float* base = ws + (size_t)b * (NBLK * OUT_);

    float s = 0.f;
    #pragma unroll 4
    for (int i = 0; i < (NBLK * OUT_) / 640; ++i)   // 16
        s += base[j + i * 640];

    __shared__ float lds[640];
    lds[j] = s;
    __syncthreads();

    if (j < OUT_) {
        float tot = dec_b[j];
        #pragma unroll
        for (int lc = 0; lc < 64; ++lc) tot += lds[lc * OUT_ + j];
        out[b * OUT_ + j] = tot;
    }
}

extern "C" void kernel_launch(void* const* d_in, const int* in_sizes, int n_in,
                              void* d_out, int out_size, void* d_ws, size_t ws_size,
                              hipStream_t stream) {
    const float* x     = (const float*)d_in[0];
    const float* wgt   = (const float*)d_in[1];
    const float* bias  = (const float*)d_in[2];
    const float* dec_w = (const float*)d_in[3];
    const float* dec_b = (const float*)d_in[4];
    float* out = (float*)d_out;
    float* wsf = (float*)d_ws;   // 64*1024*10*4 = 2.62 MB

    lcn_main<<<dim3(NBLK), dim3(512), 0, stream>>>(x, wgt, bias, dec_w, wsf);
    lcn_reduce<<<dim3(B_), dim3(640), 0, stream>>>(wsf, dec_b, out);
}

// Round 8
// 235.988 us; speedup vs baseline: 1.2770x; 1.2770x over previous
//
#include <hip/hip_runtime.h>
#include <hip/hip_bf16.h>

// B=64, C=1, H=W=1024, KS=16, F=128, OUT=10, L=4096, K=256
#define B_    64
#define F_    128
#define L_    4096
#define K_    256
#define OUT_  10
#define HW_   (1024 * 1024)
#define WIMG_ 1024

typedef __attribute__((ext_vector_type(8))) short bf16x8;   // MFMA A/B frag
typedef __attribute__((ext_vector_type(4))) float f32x4;    // MFMA C/D frag

static __device__ __forceinline__ unsigned short f2bf(float f) {
    return __builtin_bit_cast(unsigned short, __float2bfloat16(f));
}

// ---------------------------------------------------------------------------
// One block per l, 512 threads = 8 waves (2 b-halves x 4 f-quarters).
// KEY CHANGE vs R7: w is staged to LDS in 2 K-phases (wm[128 f][128 k] bf16,
// 32KB/phase), and each w-stage INSTRUCTION reads 2 contiguous 512B segments
// (lanes 0-31 -> row f, 32-63 -> row f+1) instead of 16 scattered 128B
// segments. Tests the per-instruction DRAM-coalescing hypothesis directly.
// xs[64][256] bf16 (32KB) staged once. LDS = 64KB exactly (static limit).
// acc[2][2] accumulates across both K-phases. R5's proven fused epilogue.
// ---------------------------------------------------------------------------
__global__ __launch_bounds__(512)
void lcn_main(const float* __restrict__ x, const float* __restrict__ wgt,
              const float* __restrict__ bias, const float* __restrict__ dec_w,
              float* __restrict__ ws) {
    const int l  = blockIdx.x;
    const int hb = l >> 6, wb = l & 63;
    const int t  = threadIdx.x;
    const int lane = t & 63;
    const int wid  = t >> 6;        // 0..7
    const int ln15 = lane & 15;
    const int kg   = lane >> 4;     // 0..3
    const int wm2  = wid >> 2;      // b-half (0..1)
    const int wf   = wid & 3;       // f-quarter (0..3)

    __shared__ union {
        struct { unsigned short xs[B_ * K_]; unsigned short wm[F_ * 128]; } s; // 32+32 KB
        float ysm[B_][132];          // 33.8 KB (after main loop)
        float red[16][B_][OUT_];     // 40 KB   (after ysm reads)
    } u;   // 65536 B total

    // ---- stage x: wave wid covers b-planes wid*8..+7; per instr one plane,
    //      16 rows x 64B (x's irreducible granule). ----
    {
        const int xrow = lane >> 2, xc4 = (lane & 3) * 4;
        const float* xb = x + (size_t)(hb * 16 + xrow) * WIMG_ + wb * 16 + xc4;
        #pragma unroll
        for (int i = 0; i < 8; ++i) {
            const int b = wid * 8 + i;
            float4 v = *reinterpret_cast<const float4*>(xb + (size_t)b * HW_);
            const int k = xrow * 16 + xc4;
            *reinterpret_cast<ushort4*>(&u.s.xs[b * K_ + (k ^ ((b & 7) << 3))]) =
                make_ushort4(f2bf(v.x), f2bf(v.y), f2bf(v.z), f2bf(v.w));
        }
    }

    f32x4 acc[2][2];
    #pragma unroll
    for (int m = 0; m < 2; ++m)
        #pragma unroll
        for (int n = 0; n < 2; ++n)
            acc[m][n] = (f32x4){0.f, 0.f, 0.f, 0.f};

    // ---- 2 K-phases: stage wm (contiguous 512B segs), barrier, 16 MFMAs ----
    const int wsf_ = wid * 16 + (lane >> 5);   // f base for staging (i*2 added)
    const int wk4  = (lane & 31) * 4;          // k_local float offset (0..124)
    #pragma unroll
    for (int p = 0; p < 2; ++p) {
        if (p) __syncthreads();   // b2: phase-0 wm reads done before overwrite
        #pragma unroll
        for (int i = 0; i < 8; ++i) {
            const int f = wsf_ + i * 2;        // lanes 0-31: f, 32-63: f+1
            float4 v = *reinterpret_cast<const float4*>(
                wgt + ((size_t)f * L_ + l) * K_ + p * 128 + wk4);
            *reinterpret_cast<ushort4*>(&u.s.wm[f * 128 + (wk4 ^ ((f & 7) << 3))]) =
                make_ushort4(f2bf(v.x), f2bf(v.y), f2bf(v.z), f2bf(v.w));
        }
        __syncthreads();          // b1/b3: wm (and xs on p=0) ready

        #pragma unroll
        for (int ks = 0; ks < 4; ++ks) {
            const int kloc = ks * 32 + kg * 8;
            bf16x8 a[2], bb[2];
            #pragma unroll
            for (int m = 0; m < 2; ++m) {
                const int b = wm2 * 32 + m * 16 + ln15;
                a[m] = *reinterpret_cast<const bf16x8*>(
                    &u.s.xs[b * K_ + ((p * 128 + kloc) ^ ((b & 7) << 3))]);
            }
            #pragma unroll
            for (int n = 0; n < 2; ++n) {
                const int f = wf * 32 + n * 16 + ln15;
                bb[n] = *reinterpret_cast<const bf16x8*>(
                    &u.s.wm[f * 128 + (kloc ^ ((f & 7) << 3))]);
            }
            #pragma unroll
            for (int m = 0; m < 2; ++m)
                #pragma unroll
                for (int n = 0; n < 2; ++n)
                    acc[m][n] = __builtin_amdgcn_mfma_f32_16x16x32_bf16(
                        a[m], bb[n], acc[m][n], 0, 0, 0);
        }
    }

    // ---- epilogue: bias + ReLU -> ysm ----
    float bv[2];
    #pragma unroll
    for (int n = 0; n < 2; ++n)
        bv[n] = bias[(size_t)(wf * 32 + n * 16 + ln15) * L_ + l];

    __syncthreads();   // b4: all xs/wm reads done before ysm overwrites union

    #pragma unroll
    for (int m = 0; m < 2; ++m)
        #pragma unroll
        for (int n = 0; n < 2; ++n)
            #pragma unroll
            for (int r = 0; r < 4; ++r) {
                const int b = wm2 * 32 + m * 16 + kg * 4 + r;  // C/D row map
                const int f = wf * 32 + n * 16 + ln15;         // C/D col map
                u.ysm[b][f] = fmaxf(acc[m][n][r] + bv[n], 0.f);
            }
    __syncthreads();   // b5

    // ---- fused decoder (proven R5 pattern): (oh) x (tx,ty) owns 4b x 8f ----
    const int tt = t & 255;
    const int oh = t >> 8;               // o-half: 0 -> o0..4, 1 -> o5..9
    const int tx = tt & 15, ty = tt >> 4;
    const int b0 = tx * 4, f0 = ty * 8;

    float yv[4][8];
    #pragma unroll
    for (int bi = 0; bi < 4; ++bi) {
        f32x4 p0 = *reinterpret_cast<const f32x4*>(&u.ysm[b0 + bi][f0]);
        f32x4 p1 = *reinterpret_cast<const f32x4*>(&u.ysm[b0 + bi][f0 + 4]);
        yv[bi][0] = p0.x; yv[bi][1] = p0.y; yv[bi][2] = p0.z; yv[bi][3] = p0.w;
        yv[bi][4] = p1.x; yv[bi][5] = p1.y; yv[bi][6] = p1.z; yv[bi][7] = p1.w;
    }
    __syncthreads();   // b6: ysm reads done before red overwrites the union

    float part[4][5];
    #pragma unroll
    for (int bi = 0; bi < 4; ++bi)
        #pragma unroll
        for (int oo = 0; oo < 5; ++oo) part[bi][oo] = 0.f;

    #pragma unroll
    for (int fj = 0; fj < 8; ++fj) {
        #pragma unroll
        for (int oo = 0; oo < 5; ++oo) {
            const int o = oh * 5 + oo;
            const float dw = dec_w[(size_t)o * ((size_t)F_ * L_) + (size_t)(f0 + fj) * L_ + l];
            #pragma unroll
            for (int bi = 0; bi < 4; ++bi)
                part[bi][oo] = fmaf(yv[bi][fj], dw, part[bi][oo]);
        }
    }

    #pragma unroll
    for (int bi = 0; bi < 4; ++bi)
        #pragma unroll
        for (int oo = 0; oo < 5; ++oo)
            u.red[ty][b0 + bi][oh * 5 + oo] = part[bi][oo];
    __syncthreads();   // b7

    for (int idx = t; idx < B_ * OUT_; idx += 512) {
        const int b = idx / OUT_;
        const int o = idx - b * OUT_;
        float s = 0.f;
        #pragma unroll
        for (int g = 0; g < 16; ++g) s += u.red[g][b][o];
        ws[(size_t)b * ((size_t)L_ * OUT_) + (size_t)l * OUT_ + o] = s;
    }
}

// ---------------------------------------------------------------------------
// Kernel B: reduce ws over l, add dec_b.
// ---------------------------------------------------------------------------
__global__ __launch_bounds__(640)
void lcn_reduce(const float* __restrict__ ws, const float* __restrict__ dec_b,
                float* __restrict__ out) {
    const int b = blockIdx.x;
    const int j = threadIdx.x;            // 0..639
    const float* base = ws + (size_t)b * ((size_t)L_ * OUT_);

    float s = 0.f;
    #pragma unroll 8
    for (int i = 0; i < 64; ++i)
        s += base[j + i * (64 * OUT_)];

    __shared__ float lds[64 * OUT_];
    lds[j] = s;
    __syncthreads();

    if (j < OUT_) {
        float tot = dec_b[j];
        #pragma unroll
        for (int lc = 0; lc < 64; ++lc) tot += lds[lc * OUT_ + j];
        out[b * OUT_ + j] = tot;
    }
}

extern "C" void kernel_launch(void* const* d_in, const int* in_sizes, int n_in,
                              void* d_out, int out_size, void* d_ws, size_t ws_size,
                              hipStream_t stream) {
    const float* x     = (const float*)d_in[0];
    const float* wgt   = (const float*)d_in[1];
    const float* bias  = (const float*)d_in[2];
    const float* dec_w = (const float*)d_in[3];
    const float* dec_b = (const float*)d_in[4];
    float* out = (float*)d_out;
    float* wsf = (float*)d_ws;   // 64*4096*10*4 = 10.49 MB

    lcn_main<<<dim3(L_), dim3(512), 0, stream>>>(x, wgt, bias, dec_w, wsf);
    lcn_reduce<<<dim3(B_), dim3(640), 0, stream>>>(wsf, dec_b, out);
}